// Round 1
// 898.452 us; speedup vs baseline: 1.0822x; 1.0822x over previous
//
#include <hip/hip_runtime.h>

typedef __bf16 bf16;
typedef __bf16 bf16x8 __attribute__((ext_vector_type(8)));
typedef __bf16 bf16x4 __attribute__((ext_vector_type(4)));
typedef float  f32x4  __attribute__((ext_vector_type(4)));

// Problem constants: B=32, N=1024, DIM=1152, H=12, KV=4, D=96, G=3, P=3, LS=32

static __device__ __forceinline__ float load_any(const void* p, size_t i, int isbf) {
  return isbf ? (float)((const bf16*)p)[i] : ((const float*)p)[i];
}

// async global->LDS, 16 bytes per lane. LDS dest is wave-uniform base + lane*16:
// callers MUST compute l = lds_base + lane*16 in wave-lane order (no padding).
static __device__ __forceinline__ void cp16(const bf16* g, bf16* l) {
  __builtin_amdgcn_global_load_lds(
      (const __attribute__((address_space(1))) void*)g,
      (__attribute__((address_space(3))) void*)l, 16, 0, 0);
}

// ---------------- dtype detect ----------------
__global__ void k_detect(const unsigned int* __restrict__ x, int* __restrict__ flag) {
  __shared__ int cnt[256];
  unsigned int w = x[(size_t)threadIdx.x * 65536u + 123u];
  unsigned int lo = w & 0xffffu;
  int e = (int)((lo >> 7) & 0xffu);
  cnt[threadIdx.x] = (lo == 0u) || (e >= 100 && e <= 140);
  __syncthreads();
  for (int s = 128; s > 0; s >>= 1) {
    if ((int)threadIdx.x < s) cnt[threadIdx.x] += cnt[threadIdx.x + s];
    __syncthreads();
  }
  if (threadIdx.x == 0) *flag = (cnt[0] >= 128) ? 1 : 0;
}

// ---------------- small params -> fp32; zero focus accumulators ----------------
// pbuf: [0,1152) wq_b | [1152,1920) wkv_b | [1920,5376) dwc_w | [5376,5760) dwc_b | [5760,6912) proj_b
// NOTE: wq_b then wkv_b contiguous -> fused-gemm bias is pbuf+0 over 1920 cols.
__global__ void k_prep(const void* wq_b, const void* wkv_b, const void* dwc_w,
                       const void* dwc_b, const void* proj_b,
                       float* __restrict__ pbuf, float* __restrict__ acc,
                       const int* __restrict__ flagp) {
  int isbf = *flagp;
  int i = blockIdx.x * 256 + threadIdx.x;
  if (i < 1024) acc[i] = 0.f;
  if (i >= 6912) return;
  float v;
  if (i < 1152)      v = load_any(wq_b,   i,        isbf);
  else if (i < 1920) v = load_any(wkv_b,  i - 1152, isbf);
  else if (i < 5376) v = load_any(dwc_w,  i - 1920, isbf);
  else if (i < 5760) v = load_any(dwc_b,  i - 5376, isbf);
  else               v = load_any(proj_b, i - 5760, isbf);
  pbuf[i] = v;
}

// ---------------- weight transpose -> bf16 [out][in] ----------------
__global__ __launch_bounds__(256) void k_transpose(const void* __restrict__ in,
    bf16* __restrict__ out, int R, int C, const int* __restrict__ flagp) {
  int isbf = *flagp;
  __shared__ bf16 tile[32][33];
  int c0 = blockIdx.x * 32, r0 = blockIdx.y * 32;
  int tx = threadIdx.x & 31, ty = threadIdx.x >> 5;
  for (int i = ty; i < 32; i += 8) {
    int r = r0 + i, c = c0 + tx;
    float v = (r < R && c < C) ? load_any(in, (size_t)r * C + c, isbf) : 0.f;
    tile[i][tx] = (bf16)v;
  }
  __syncthreads();
  for (int i = ty; i < 32; i += 8) {
    int c = c0 + i, r = r0 + tx;
    if (c < C && r < R) out[(size_t)c * R + r] = tile[tx][i];
  }
}

// ---------------- x ingest -> bf16 (fp32 mode only; bf16 mode reads x directly) ----------------
__global__ void k_ingest(const void* __restrict__ x, bf16* __restrict__ xb,
                         const int* __restrict__ flagp) {
  if (*flagp) return;
  size_t i = ((size_t)blockIdx.x * 256 + threadIdx.x) * 8;
  if (i >= (size_t)37748736) return;
  const float4* xf = (const float4*)((const float*)x + i);
  float4 a = xf[0], b = xf[1];
  bf16x8 o = {(bf16)a.x, (bf16)a.y, (bf16)a.z, (bf16)a.w,
              (bf16)b.x, (bf16)b.y, (bf16)b.z, (bf16)b.w};
  *(bf16x8*)(xb + i) = o;
}

// ---------------- MFMA GEMM: C[M,N] = A[M,K] @ Bt[N,K]^T + bias ----------------
// m97 structure: 128x128 tile, BK=32, global_load_lds width=16 into UNPADDED
// [128][32] LDS. 4 waves, each a 64x64 quadrant of 4x4 16x16x32 mfma.
// out_mode: 0 = fp32 C, 1 = dtype per flag (d_out).
// focus!=0: fused relu^2/relu^6 Frobenius partial sums into facc:
//   cols [0,1152)    -> q group  b*12 + col/96
//   cols [1152,1536) -> k group  384 + b*4 + (col/96 - 12)
//   cols [1536,1920) -> v, no focus
// Block col-span is 128 => exactly heads {h0, h0+1} (h0=n0/96), never straddling
// the q/k/v boundaries (multiples of 96 align with 128-blocks at 1152/1536).
__global__ __launch_bounds__(256) void k_gemm(const bf16* __restrict__ A,
    const bf16* __restrict__ Aalt, int asel,
    const bf16* __restrict__ Bt, const float* __restrict__ bias,
    void* __restrict__ Cv, int M, int N, int K, int ldc, int out_mode, int focus,
    float* __restrict__ facc, const int* __restrict__ flagp) {
  __shared__ bf16 sA[128 * 32];
  __shared__ bf16 sB[128 * 32];
  __shared__ float fsh[4];   // [s2_p0, s2_p1, s6_p0, s6_p1] by head parity
  const int t = threadIdx.x;
  const int m0 = blockIdx.x * 128, n0 = blockIdx.y * 128;
  const int wave = t >> 6, lane = t & 63, quad = lane >> 4, l16 = lane & 15;
  const int wm = (wave >> 1) * 64, wn = (wave & 1) * 64;
  const int flg = *flagp;
  const bf16* Asrc = (asel && flg) ? Aalt : A;
  const int srow_base = wave * 32 + (lane >> 2);
  const int scol = (lane & 3) * 8;
  if (t < 4) fsh[t] = 0.f;
  f32x4 acc[4][4];
  f32x4 zero = {0.f, 0.f, 0.f, 0.f};
#pragma unroll
  for (int i = 0; i < 4; i++)
#pragma unroll
    for (int j = 0; j < 4; j++) acc[i][j] = zero;

  for (int k0 = 0; k0 < K; k0 += 32) {
#pragma unroll
    for (int it = 0; it < 2; it++) {
      int row = srow_base + it * 16;
      cp16(Asrc + (size_t)(m0 + row) * K + k0 + scol, sA + row * 32 + scol);
      cp16(Bt   + (size_t)(n0 + row) * K + k0 + scol, sB + row * 32 + scol);
    }
    __syncthreads();
    bf16x8 af[4], bfr[4];
#pragma unroll
    for (int i = 0; i < 4; i++) af[i]  = *(const bf16x8*)&sA[(wm + i * 16 + l16) * 32 + quad * 8];
#pragma unroll
    for (int j = 0; j < 4; j++) bfr[j] = *(const bf16x8*)&sB[(wn + j * 16 + l16) * 32 + quad * 8];
#pragma unroll
    for (int i = 0; i < 4; i++)
#pragma unroll
      for (int j = 0; j < 4; j++)
        acc[i][j] = __builtin_amdgcn_mfma_f32_16x16x32_bf16(af[i], bfr[j], acc[i][j], 0, 0, 0);
    __syncthreads();
  }
  const bool obf = (out_mode != 0) && (flg != 0);
  const bool do_focus = (focus != 0) && (n0 < 1536);
  float fs2[2] = {0.f, 0.f}, fs6[2] = {0.f, 0.f};
#pragma unroll
  for (int j = 0; j < 4; j++) {
    int col = n0 + wn + j * 16 + l16;
    float bv = bias[col];
    float s2 = 0.f, s6 = 0.f;
#pragma unroll
    for (int i = 0; i < 4; i++) {
#pragma unroll
      for (int r = 0; r < 4; r++) {
        int row = m0 + wm + i * 16 + quad * 4 + r;
        float v = acc[i][j][r] + bv;
        if (obf) ((bf16*)Cv)[(size_t)row * ldc + col] = (bf16)v;
        else     ((float*)Cv)[(size_t)row * ldc + col] = v;
        float tt = fmaxf(v, 0.f);
        float t2 = tt * tt;
        s2 += t2; s6 += t2 * t2 * t2;
      }
    }
    int pj = (col / 96) & 1;   // head parity; uniform per (wave,j): 96 % 16 == 0
    fs2[pj] += s2; fs6[pj] += s6;
  }
  if (do_focus) {
    // wave butterfly reduce the 4 partials, 1 LDS atomic per wave per value
#pragma unroll
    for (int m = 1; m < 64; m <<= 1) {
      fs2[0] += __shfl_xor(fs2[0], m);
      fs2[1] += __shfl_xor(fs2[1], m);
      fs6[0] += __shfl_xor(fs6[0], m);
      fs6[1] += __shfl_xor(fs6[1], m);
    }
    if (lane == 0) {
      atomicAdd(&fsh[0], fs2[0]);
      atomicAdd(&fsh[1], fs2[1]);
      atomicAdd(&fsh[2], fs6[0]);
      atomicAdd(&fsh[3], fs6[1]);
    }
    __syncthreads();
    if (t < 2) {
      int h0 = n0 / 96;
      int h = h0 + t;             // block always covers exactly h0 and h0+1
      int p = h & 1;
      int b = m0 >> 10;           // 128 | 1024 -> single batch per block
      int g = (h < 12) ? (b * 12 + h) : (384 + b * 4 + (h - 12));
      atomicAdd(&facc[g * 2],     fsh[p]);
      atomicAdd(&facc[g * 2 + 1], fsh[2 + p]);
    }
  }
}

// focus stage 2: scale[g] = sqrt(s2/s6)   (g in [0,512): 384 q-groups then 128 k-groups)
__global__ void k_scales(const float* __restrict__ acc, float* __restrict__ scale) {
  int i = blockIdx.x * 256 + threadIdx.x;
  if (i < 512) scale[i] = sqrtf(acc[i * 2] / acc[i * 2 + 1]);
}

// ---------------- kv einsum, split-K partials (k,v from fused C, ldc=1920) ----------------
__global__ __launch_bounds__(256) void k_kvein_part(const float* __restrict__ Cq,
    float* __restrict__ part) {
  int blk = blockIdx.x;                 // g*8 + c
  int g = blk >> 3, c = blk & 7;
  const float* kbase = Cq + (size_t)(g >> 2) * 1024 * 1920 + 1152 + (g & 3) * 96
                     + (size_t)c * 128 * 1920;
  const float* vbase = kbase + 384;
  __shared__ float sk[32][96];
  __shared__ float sv[32][96];
  int ty = threadIdx.x >> 4, tx = threadIdx.x & 15;
  float acc[6][6];
#pragma unroll
  for (int i = 0; i < 6; i++)
#pragma unroll
    for (int j = 0; j < 6; j++) acc[i][j] = 0.f;
  for (int nc = 0; nc < 128; nc += 32) {
    __syncthreads();
    for (int i = threadIdx.x; i < 32 * 24; i += 256) {
      int n = i / 24, d4 = (i - n * 24) * 4;
      float4 kk = *(const float4*)(kbase + (size_t)(nc + n) * 1920 + d4);
      float4 vv = *(const float4*)(vbase + (size_t)(nc + n) * 1920 + d4);
      float tv;
      tv = fmaxf(kk.x, 0.f); sk[n][d4 + 0] = tv * tv * tv;
      tv = fmaxf(kk.y, 0.f); sk[n][d4 + 1] = tv * tv * tv;
      tv = fmaxf(kk.z, 0.f); sk[n][d4 + 2] = tv * tv * tv;
      tv = fmaxf(kk.w, 0.f); sk[n][d4 + 3] = tv * tv * tv;
      sv[n][d4 + 0] = vv.x; sv[n][d4 + 1] = vv.y;
      sv[n][d4 + 2] = vv.z; sv[n][d4 + 3] = vv.w;
    }
    __syncthreads();
#pragma unroll 4
    for (int n = 0; n < 32; n++) {
      float kr[6], vr[6];
#pragma unroll
      for (int i = 0; i < 6; i++) kr[i] = sk[n][ty * 6 + i];
#pragma unroll
      for (int j = 0; j < 6; j++) vr[j] = sv[n][tx * 6 + j];
#pragma unroll
      for (int i = 0; i < 6; i++)
#pragma unroll
        for (int j = 0; j < 6; j++) acc[i][j] += kr[i] * vr[j];
    }
  }
  float* out = part + (size_t)blk * 9216;
#pragma unroll
  for (int i = 0; i < 6; i++)
#pragma unroll
    for (int j = 0; j < 6; j++)
      out[(ty * 6 + i) * 96 + tx * 6 + j] = acc[i][j];   // [dk][e]
}

// reduce 8 partials, scale, store transposed bf16: KVT[g][e][dk]
__global__ void k_kvred(const float* __restrict__ part, const float* __restrict__ sck,
                        bf16* __restrict__ KVT) {
  int t = blockIdx.x * 256 + threadIdx.x;   // over 128*9216
  if (t >= 1179648) return;
  int g = t / 9216, r = t - g * 9216;
  int dk = r / 96, e = r - dk * 96;
  const float* p = part + (size_t)g * 8 * 9216 + r;
  float s = 0.f;
#pragma unroll
  for (int c = 0; c < 8; c++) s += p[(size_t)c * 9216];
  KVT[(size_t)g * 9216 + e * 96 + dk] = (bf16)(sck[g] * s);
}

// ---------------- depthwise 3x3 conv on 32x32 latent grid (v from fused C) ----------------
__global__ void k_dwc(const float* __restrict__ Cq, const float* __restrict__ pw,
                      const float* __restrict__ pb, bf16* __restrict__ VD) {
  int idx = blockIdx.x * 256 + threadIdx.x;            // [B][KV][1024][96]
  if (idx >= 32 * 4 * 1024 * 96) return;
  int d  = idx % 96;
  int n  = (idx / 96) & 1023;
  int kv = (idx / (96 * 1024)) & 3;
  int b  = idx / (96 * 1024 * 4);
  int y = n >> 5, x = n & 31;
  int c = kv * 96 + d;
  const float* w = pw + c * 9;
  float acc = pb[c];
  const float* vb = Cq + (size_t)b * 1024 * 1920 + 1536 + c;
#pragma unroll
  for (int dy = -1; dy <= 1; dy++) {
    int yy = y + dy;
    if (yy < 0 || yy >= 32) continue;
#pragma unroll
    for (int dx = -1; dx <= 1; dx++) {
      int xx = x + dx;
      if (xx < 0 || xx >= 32) continue;
      acc += w[(dy + 1) * 3 + (dx + 1)] * vb[(size_t)((yy << 5) + xx) * 1920];
    }
  }
  VD[idx] = (bf16)acc;
}

// ---------------- attn: OC[b,n,h*96+d] = focus(q)[b,h] @ kv[b,h%4] + vdwc[b,h%4] ----------------
// q read raw fp32 from fused C; sc*relu(q)^3 applied during LDS staging (ex-k_qf).
__global__ __launch_bounds__(256) void k_attn(const float* __restrict__ Cq,
    const float* __restrict__ scq, const bf16* __restrict__ KVT,
    const bf16* __restrict__ VD, bf16* __restrict__ OC) {
  int bh = blockIdx.x;
  int b = bh / 12, h = bh - b * 12;
  int kvh = h & 3;                    // jnp.tile -> head h uses kv-head h % 4
  int n0 = blockIdx.y * 64;
  __shared__ bf16 sQ[64][104];
  __shared__ bf16 sKV[96][104];
  int t = threadIdx.x;
  float sc = scq[b * 12 + h];
  const float* qsrc = Cq + (size_t)(b * 1024 + n0) * 1920 + h * 96;
  for (int i = t; i < 64 * 24; i += 256) {
    int row = i / 24, seg = (i - row * 24) * 4;
    float4 q4 = *(const float4*)(qsrc + (size_t)row * 1920 + seg);
    bf16x4 o;
    float tv;
    tv = fmaxf(q4.x, 0.f); o[0] = (bf16)(sc * tv * tv * tv);
    tv = fmaxf(q4.y, 0.f); o[1] = (bf16)(sc * tv * tv * tv);
    tv = fmaxf(q4.z, 0.f); o[2] = (bf16)(sc * tv * tv * tv);
    tv = fmaxf(q4.w, 0.f); o[3] = (bf16)(sc * tv * tv * tv);
    *(bf16x4*)&sQ[row][seg] = o;
  }
  const bf16* kvsrc = KVT + (size_t)(b * 4 + kvh) * 9216;
  for (int i = t; i < 96 * 12; i += 256) {
    int row = i / 12, seg = (i - row * 12) * 8;
    *(bf16x8*)&sKV[row][seg] = *(const bf16x8*)(kvsrc + row * 96 + seg);
  }
  __syncthreads();
  int wave = t >> 6, lane = t & 63, quad = lane >> 4, l16 = lane & 15;
  f32x4 acc[6];
  f32x4 zero = {0.f, 0.f, 0.f, 0.f};
#pragma unroll
  for (int j = 0; j < 6; j++) acc[j] = zero;
#pragma unroll
  for (int k0 = 0; k0 < 96; k0 += 32) {
    bf16x8 a = *(const bf16x8*)&sQ[wave * 16 + l16][k0 + quad * 8];
#pragma unroll
    for (int j = 0; j < 6; j++) {
      bf16x8 bb = *(const bf16x8*)&sKV[j * 16 + l16][k0 + quad * 8];
      acc[j] = __builtin_amdgcn_mfma_f32_16x16x32_bf16(a, bb, acc[j], 0, 0, 0);
    }
  }
  const bf16* vd = VD + ((size_t)(b * 4 + kvh) * 1024 + n0) * 96;
  bf16* oc = OC + (size_t)(b * 1024 + n0) * 1152 + h * 96;
#pragma unroll
  for (int j = 0; j < 6; j++) {
    int col = j * 16 + l16;
#pragma unroll
    for (int r = 0; r < 4; r++) {
      int row = wave * 16 + quad * 4 + r;
      float v = acc[j][r] + (float)vd[(size_t)row * 96 + col];
      oc[(size_t)row * 1152 + col] = (bf16)v;
    }
  }
}

// ---------------- launch ----------------
extern "C" void kernel_launch(void* const* d_in, const int* in_sizes, int n_in,
                              void* d_out, int out_size, void* d_ws, size_t ws_size,
                              hipStream_t stream) {
  (void)in_sizes; (void)n_in; (void)out_size; (void)ws_size;
  const void* x      = d_in[0];
  const void* wq_w   = d_in[1];
  const void* wq_b   = d_in[2];
  const void* wkv_w  = d_in[3];
  const void* wkv_b  = d_in[4];
  const void* dwc_w  = d_in[5];
  const void* dwc_b  = d_in[6];
  const void* proj_w = d_in[7];
  const void* proj_b = d_in[8];

  char* ws = (char*)d_ws;
  size_t off = 0;
  auto alloc = [&](size_t bytes) -> void* {
    void* p = ws + off;
    off = (off + bytes + 255) & ~(size_t)255;
    return p;
  };
  int*   flag   = (int*)  alloc(256);
  float* pbuf   = (float*)alloc((size_t)6912 * 4);
  float* facc   = (float*)alloc(1024 * 4);               // 512 groups x (s2,s6)
  float* scale  = (float*)alloc(512 * 4);                // [0,384) q | [384,512) k
  bf16*  wcat_t = (bf16*) alloc((size_t)1920 * 1152 * 2);// [wq_t; wkv_t] rows 0..1919
  bf16*  proj_t = (bf16*) alloc((size_t)1152 * 1152 * 2);
  bf16*  xb     = (bf16*) alloc((size_t)37748736 * 2);   // x bf16 (fp32 mode); reused as out_comb
  float* cq     = (float*)alloc((size_t)32768 * 1920 * 4); // fused q|k|v fp32
  float* part   = (float*)alloc((size_t)1024 * 9216 * 4);  // kv einsum partials
  bf16*  kvt    = (bf16*) alloc((size_t)128 * 9216 * 2);
  bf16*  vdwc   = (bf16*) alloc((size_t)32 * 4 * 1024 * 96 * 2);

  k_detect<<<1, 256, 0, stream>>>((const unsigned int*)x, flag);
  k_prep<<<27, 256, 0, stream>>>(wq_b, wkv_b, dwc_w, dwc_b, proj_b, pbuf, facc, flag);
  k_transpose<<<dim3(36, 36), 256, 0, stream>>>(wq_w, wcat_t, 1152, 1152, flag);
  k_transpose<<<dim3(24, 36), 256, 0, stream>>>(wkv_w, wcat_t + (size_t)1152 * 1152, 1152, 768, flag);
  k_transpose<<<dim3(36, 36), 256, 0, stream>>>(proj_w, proj_t, 1152, 1152, flag);
  k_ingest<<<18432, 256, 0, stream>>>(x, xb, flag);

  const bf16* xbf = (const bf16*)x;

  // fused [q | kv] = x @ [wq | wkv] + b, fp32 out, focus sums fused into epilogue
  k_gemm<<<dim3(256, 15), 256, 0, stream>>>(xb, xbf, 1, wcat_t, pbuf + 0, (void*)cq,
                                            32768, 1920, 1152, 1920, 0, 1, facc, flag);
  k_scales<<<2, 256, 0, stream>>>(facc, scale);

  k_kvein_part<<<1024, 256, 0, stream>>>(cq, part);
  k_kvred<<<4608, 256, 0, stream>>>(part, scale + 384, kvt);

  k_dwc<<<49152, 256, 0, stream>>>(cq, pbuf + 1920, pbuf + 5376, vdwc);
  k_attn<<<dim3(384, 16), 256, 0, stream>>>(cq, scale, kvt, vdwc, xb /* out_comb */);

  // final: out = out_comb @ proj + b  -> d_out (dtype per detected flag)
  k_gemm<<<dim3(256, 9), 256, 0, stream>>>(xb, nullptr, 0, proj_t, pbuf + 5760, d_out,
                                           32768, 1152, 1152, 1152, 1, 0, facc, flag);
}

// Round 2
// 822.583 us; speedup vs baseline: 1.1820x; 1.0922x over previous
//
#include <hip/hip_runtime.h>

typedef __bf16 bf16;
typedef __bf16 bf16x8 __attribute__((ext_vector_type(8)));
typedef __bf16 bf16x4 __attribute__((ext_vector_type(4)));
typedef float  f32x4  __attribute__((ext_vector_type(4)));

// Problem constants: B=32, N=1024, DIM=1152, H=12, KV=4, D=96, G=3, P=3, LS=32

static __device__ __forceinline__ float load_any(const void* p, size_t i, int isbf) {
  return isbf ? (float)((const bf16*)p)[i] : ((const float*)p)[i];
}

// async global->LDS, 16 bytes per lane. LDS dest is wave-uniform base + lane*16:
// callers MUST compute l = lds_base + lane*16 in wave-lane order (no padding).
static __device__ __forceinline__ void cp16(const bf16* g, bf16* l) {
  __builtin_amdgcn_global_load_lds(
      (const __attribute__((address_space(1))) void*)g,
      (__attribute__((address_space(3))) void*)l, 16, 0, 0);
}

// ---------------- dtype detect ----------------
__global__ void k_detect(const unsigned int* __restrict__ x, int* __restrict__ flag) {
  __shared__ int cnt[256];
  unsigned int w = x[(size_t)threadIdx.x * 65536u + 123u];
  unsigned int lo = w & 0xffffu;
  int e = (int)((lo >> 7) & 0xffu);
  cnt[threadIdx.x] = (lo == 0u) || (e >= 100 && e <= 140);
  __syncthreads();
  for (int s = 128; s > 0; s >>= 1) {
    if ((int)threadIdx.x < s) cnt[threadIdx.x] += cnt[threadIdx.x + s];
    __syncthreads();
  }
  if (threadIdx.x == 0) *flag = (cnt[0] >= 128) ? 1 : 0;
}

// ---------------- small params -> fp32; zero focus accumulators ----------------
// pbuf: [0,1152) wq_b | [1152,1920) wkv_b | [1920,5376) dwc_w | [5376,5760) dwc_b
//       | [5760,6912) proj_b | [6912,10368) dwc_w transposed tap-major [9][384]
// NOTE: wq_b then wkv_b contiguous -> fused-gemm bias is pbuf+0 over 1920 cols.
__global__ void k_prep(const void* wq_b, const void* wkv_b, const void* dwc_w,
                       const void* dwc_b, const void* proj_b,
                       float* __restrict__ pbuf, float* __restrict__ acc,
                       const int* __restrict__ flagp) {
  int isbf = *flagp;
  int i = blockIdx.x * 256 + threadIdx.x;
  if (i < 1024) acc[i] = 0.f;
  if (i >= 10368) return;
  float v;
  if (i < 1152)      v = load_any(wq_b,   i,        isbf);
  else if (i < 1920) v = load_any(wkv_b,  i - 1152, isbf);
  else if (i < 5376) v = load_any(dwc_w,  i - 1920, isbf);
  else if (i < 5760) v = load_any(dwc_b,  i - 5376, isbf);
  else if (i < 6912) v = load_any(proj_b, i - 5760, isbf);
  else {
    int r = i - 6912, tap = r / 384, c = r - tap * 384;
    v = load_any(dwc_w, (size_t)c * 9 + tap, isbf);
  }
  pbuf[i] = v;
}

// ---------------- weight transpose -> bf16 [out][in] ----------------
__global__ __launch_bounds__(256) void k_transpose(const void* __restrict__ in,
    bf16* __restrict__ out, int R, int C, const int* __restrict__ flagp) {
  int isbf = *flagp;
  __shared__ bf16 tile[32][33];
  int c0 = blockIdx.x * 32, r0 = blockIdx.y * 32;
  int tx = threadIdx.x & 31, ty = threadIdx.x >> 5;
  for (int i = ty; i < 32; i += 8) {
    int r = r0 + i, c = c0 + tx;
    float v = (r < R && c < C) ? load_any(in, (size_t)r * C + c, isbf) : 0.f;
    tile[i][tx] = (bf16)v;
  }
  __syncthreads();
  for (int i = ty; i < 32; i += 8) {
    int c = c0 + i, r = r0 + tx;
    if (c < C && r < R) out[(size_t)c * R + r] = tile[tx][i];
  }
}

// ---------------- x ingest -> bf16 (fp32 mode only; bf16 mode reads x directly) ----------------
__global__ void k_ingest(const void* __restrict__ x, bf16* __restrict__ xb,
                         const int* __restrict__ flagp) {
  if (*flagp) return;
  size_t i = ((size_t)blockIdx.x * 256 + threadIdx.x) * 8;
  if (i >= (size_t)37748736) return;
  const float4* xf = (const float4*)((const float*)x + i);
  float4 a = xf[0], b = xf[1];
  bf16x8 o = {(bf16)a.x, (bf16)a.y, (bf16)a.z, (bf16)a.w,
              (bf16)b.x, (bf16)b.y, (bf16)b.z, (bf16)b.w};
  *(bf16x8*)(xb + i) = o;
}

// ---------------- MFMA GEMM: C[M,N] = A[M,K] @ Bt[N,K]^T + bias ----------------
// 128x128 tile, BK=32, global_load_lds width=16 into UNPADDED [128][32] LDS,
// now DOUBLE-BUFFERED (T3 minimum 2-phase: stage t+1 before compute t, one
// barrier per K-step) with N-tile-fastest block order + bijective XCD swizzle
// (T1) so consecutive blocks share an A-panel and B stays L2-resident.
// out_mode: 0 = fp32 C, 1 = dtype per flag (d_out).
// focus!=0: fused relu^2/relu^6 Frobenius partial sums into facc (see R0 notes).
__global__ __launch_bounds__(256) void k_gemm(const bf16* __restrict__ A,
    const bf16* __restrict__ Aalt, int asel,
    const bf16* __restrict__ Bt, const float* __restrict__ bias,
    void* __restrict__ Cv, int M, int N, int K, int ldc, int out_mode, int focus,
    float* __restrict__ facc, const int* __restrict__ flagp) {
  __shared__ bf16 sA[2][128 * 32];
  __shared__ bf16 sB[2][128 * 32];
  __shared__ float fsh[4];   // [s2_p0, s2_p1, s6_p0, s6_p1] by head parity
  const int t = threadIdx.x;
  // N-fastest + XCD swizzle: XCD c gets a contiguous chunk of M-panels.
  const int NT = N >> 7;
  const int nwg = (M >> 7) * NT;          // must be % 8 == 0 (3840 / 2304 ok)
  const int orig = blockIdx.x;
  const int wg = (orig & 7) * (nwg >> 3) + (orig >> 3);
  const int n0 = (wg % NT) * 128;
  const int m0 = (wg / NT) * 128;
  const int wave = t >> 6, lane = t & 63, quad = lane >> 4, l16 = lane & 15;
  const int wm = (wave >> 1) * 64, wn = (wave & 1) * 64;
  const int flg = *flagp;
  const bf16* Asrc = (asel && flg) ? Aalt : A;
  const int srow_base = wave * 32 + (lane >> 2);
  const int scol = (lane & 3) * 8;
  if (t < 4) fsh[t] = 0.f;
  f32x4 acc[4][4];
  f32x4 zero = {0.f, 0.f, 0.f, 0.f};
#pragma unroll
  for (int i = 0; i < 4; i++)
#pragma unroll
    for (int j = 0; j < 4; j++) acc[i][j] = zero;

  // stage K-tile k0 into buffer buf (4 x 16B per thread, wave-linear dest)
  auto stage = [&](int k0, int buf) {
#pragma unroll
    for (int it = 0; it < 2; it++) {
      int row = srow_base + it * 16;
      cp16(Asrc + (size_t)(m0 + row) * K + k0 + scol, &sA[buf][row * 32 + scol]);
      cp16(Bt   + (size_t)(n0 + row) * K + k0 + scol, &sB[buf][row * 32 + scol]);
    }
  };
  auto compute = [&](int buf) {
    bf16x8 af[4], bfr[4];
#pragma unroll
    for (int i = 0; i < 4; i++)
      af[i]  = *(const bf16x8*)&sA[buf][(wm + i * 16 + l16) * 32 + quad * 8];
#pragma unroll
    for (int j = 0; j < 4; j++)
      bfr[j] = *(const bf16x8*)&sB[buf][(wn + j * 16 + l16) * 32 + quad * 8];
#pragma unroll
    for (int i = 0; i < 4; i++)
#pragma unroll
      for (int j = 0; j < 4; j++)
        acc[i][j] = __builtin_amdgcn_mfma_f32_16x16x32_bf16(af[i], bfr[j], acc[i][j], 0, 0, 0);
  };

  stage(0, 0);
  __syncthreads();                 // vmcnt(0) drain + barrier: buf0 ready
  int cur = 0;
  for (int k0 = 32; k0 < K; k0 += 32) {
    stage(k0, cur ^ 1);            // issue next tile BEFORE compute (overlap)
    compute(cur);
    __syncthreads();               // all reads of cur done; cur^1 landed
    cur ^= 1;
  }
  compute(cur);                    // last tile, no prefetch

  const bool obf = (out_mode != 0) && (flg != 0);
  const bool do_focus = (focus != 0) && (n0 < 1536);
  float fs2[2] = {0.f, 0.f}, fs6[2] = {0.f, 0.f};
#pragma unroll
  for (int j = 0; j < 4; j++) {
    int col = n0 + wn + j * 16 + l16;
    float bv = bias[col];
    float s2 = 0.f, s6 = 0.f;
#pragma unroll
    for (int i = 0; i < 4; i++) {
#pragma unroll
      for (int r = 0; r < 4; r++) {
        int row = m0 + wm + i * 16 + quad * 4 + r;
        float v = acc[i][j][r] + bv;
        if (obf) ((bf16*)Cv)[(size_t)row * ldc + col] = (bf16)v;
        else     ((float*)Cv)[(size_t)row * ldc + col] = v;
        float tt = fmaxf(v, 0.f);
        float t2 = tt * tt;
        s2 += t2; s6 += t2 * t2 * t2;
      }
    }
    int pj = (col / 96) & 1;   // head parity; uniform per (wave,j): 96 % 16 == 0
    fs2[pj] += s2; fs6[pj] += s6;
  }
  if (do_focus) {
    // wave butterfly reduce the 4 partials, 1 LDS atomic per wave per value
#pragma unroll
    for (int m = 1; m < 64; m <<= 1) {
      fs2[0] += __shfl_xor(fs2[0], m);
      fs2[1] += __shfl_xor(fs2[1], m);
      fs6[0] += __shfl_xor(fs6[0], m);
      fs6[1] += __shfl_xor(fs6[1], m);
    }
    if (lane == 0) {
      atomicAdd(&fsh[0], fs2[0]);
      atomicAdd(&fsh[1], fs2[1]);
      atomicAdd(&fsh[2], fs6[0]);
      atomicAdd(&fsh[3], fs6[1]);
    }
    __syncthreads();
    if (t < 2) {
      int h0 = n0 / 96;
      int h = h0 + t;             // block always covers exactly h0 and h0+1
      int p = h & 1;
      int b = m0 >> 10;           // 128 | 1024 -> single batch per block
      int g = (h < 12) ? (b * 12 + h) : (384 + b * 4 + (h - 12));
      atomicAdd(&facc[g * 2],     fsh[p]);
      atomicAdd(&facc[g * 2 + 1], fsh[2 + p]);
    }
  }
}

// focus stage 2: scale[g] = sqrt(s2/s6)   (g in [0,512): 384 q-groups then 128 k-groups)
__global__ void k_scales(const float* __restrict__ acc, float* __restrict__ scale) {
  int i = blockIdx.x * 256 + threadIdx.x;
  if (i < 512) scale[i] = sqrtf(acc[i * 2] / acc[i * 2 + 1]);
}

// ---------------- kv einsum, split-K partials (k,v from fused C, ldc=1920) ----------------
__global__ __launch_bounds__(256) void k_kvein_part(const float* __restrict__ Cq,
    float* __restrict__ part) {
  int blk = blockIdx.x;                 // g*8 + c
  int g = blk >> 3, c = blk & 7;
  const float* kbase = Cq + (size_t)(g >> 2) * 1024 * 1920 + 1152 + (g & 3) * 96
                     + (size_t)c * 128 * 1920;
  const float* vbase = kbase + 384;
  __shared__ float sk[32][96];
  __shared__ float sv[32][96];
  int ty = threadIdx.x >> 4, tx = threadIdx.x & 15;
  float acc[6][6];
#pragma unroll
  for (int i = 0; i < 6; i++)
#pragma unroll
    for (int j = 0; j < 6; j++) acc[i][j] = 0.f;
  for (int nc = 0; nc < 128; nc += 32) {
    __syncthreads();
    for (int i = threadIdx.x; i < 32 * 24; i += 256) {
      int n = i / 24, d4 = (i - n * 24) * 4;
      float4 kk = *(const float4*)(kbase + (size_t)(nc + n) * 1920 + d4);
      float4 vv = *(const float4*)(vbase + (size_t)(nc + n) * 1920 + d4);
      float tv;
      tv = fmaxf(kk.x, 0.f); sk[n][d4 + 0] = tv * tv * tv;
      tv = fmaxf(kk.y, 0.f); sk[n][d4 + 1] = tv * tv * tv;
      tv = fmaxf(kk.z, 0.f); sk[n][d4 + 2] = tv * tv * tv;
      tv = fmaxf(kk.w, 0.f); sk[n][d4 + 3] = tv * tv * tv;
      sv[n][d4 + 0] = vv.x; sv[n][d4 + 1] = vv.y;
      sv[n][d4 + 2] = vv.z; sv[n][d4 + 3] = vv.w;
    }
    __syncthreads();
#pragma unroll 4
    for (int n = 0; n < 32; n++) {
      float kr[6], vr[6];
#pragma unroll
      for (int i = 0; i < 6; i++) kr[i] = sk[n][ty * 6 + i];
#pragma unroll
      for (int j = 0; j < 6; j++) vr[j] = sv[n][tx * 6 + j];
#pragma unroll
      for (int i = 0; i < 6; i++)
#pragma unroll
        for (int j = 0; j < 6; j++) acc[i][j] += kr[i] * vr[j];
    }
  }
  float* out = part + (size_t)blk * 9216;
#pragma unroll
  for (int i = 0; i < 6; i++)
#pragma unroll
    for (int j = 0; j < 6; j++)
      out[(ty * 6 + i) * 96 + tx * 6 + j] = acc[i][j];   // [dk][e]
}

// reduce 8 partials, scale, store transposed bf16: KVT[g][e][dk]
__global__ void k_kvred(const float* __restrict__ part, const float* __restrict__ sck,
                        bf16* __restrict__ KVT) {
  int t = blockIdx.x * 256 + threadIdx.x;   // over 128*9216
  if (t >= 1179648) return;
  int g = t / 9216, r = t - g * 9216;
  int dk = r / 96, e = r - dk * 96;
  const float* p = part + (size_t)g * 8 * 9216 + r;
  float s = 0.f;
#pragma unroll
  for (int c = 0; c < 8; c++) s += p[(size_t)c * 9216];
  KVT[(size_t)g * 9216 + e * 96 + dk] = (bf16)(sck[g] * s);
}

// ---------------- depthwise 3x3 conv on 32x32 latent grid (v from fused C) ----------------
// float4-vectorized: thread owns 4 channels; weights pre-transposed tap-major [9][384].
__global__ void k_dwc(const float* __restrict__ Cq, const float* __restrict__ pwt,
                      const float* __restrict__ pb, bf16* __restrict__ VD) {
  int idx = blockIdx.x * 256 + threadIdx.x;            // [B][KV][1024][24] float4 groups
  if (idx >= 32 * 4 * 1024 * 24) return;
  int g4 = idx % 24;
  int n  = (idx / 24) & 1023;
  int kv = (idx / (24 * 1024)) & 3;
  int b  = idx / (24 * 1024 * 4);
  int y = n >> 5, x = n & 31;
  int c0 = kv * 96 + g4 * 4;
  float4 acc = *(const float4*)(pb + c0);
  const float* vb = Cq + (size_t)b * 1024 * 1920 + 1536 + c0;
#pragma unroll
  for (int dy = -1; dy <= 1; dy++) {
    int yy = y + dy;
    if (yy < 0 || yy >= 32) continue;
#pragma unroll
    for (int dx = -1; dx <= 1; dx++) {
      int xx = x + dx;
      if (xx < 0 || xx >= 32) continue;
      float4 wv = *(const float4*)(pwt + ((dy + 1) * 3 + (dx + 1)) * 384 + c0);
      float4 vv = *(const float4*)(vb + (size_t)((yy << 5) + xx) * 1920);
      acc.x += wv.x * vv.x; acc.y += wv.y * vv.y;
      acc.z += wv.z * vv.z; acc.w += wv.w * vv.w;
    }
  }
  bf16x4 o = {(bf16)acc.x, (bf16)acc.y, (bf16)acc.z, (bf16)acc.w};
  *(bf16x4*)(VD + (size_t)idx * 4) = o;
}

// ---------------- attn: OC[b,n,h*96+d] = focus(q)[b,h] @ kv[b,h%4] + vdwc[b,h%4] ----------------
// q read raw fp32 from fused C; sc*relu(q)^3 applied during LDS staging.
__global__ __launch_bounds__(256) void k_attn(const float* __restrict__ Cq,
    const float* __restrict__ scq, const bf16* __restrict__ KVT,
    const bf16* __restrict__ VD, bf16* __restrict__ OC) {
  int bh = blockIdx.x;
  int b = bh / 12, h = bh - b * 12;
  int kvh = h & 3;                    // jnp.tile -> head h uses kv-head h % 4
  int n0 = blockIdx.y * 64;
  __shared__ bf16 sQ[64][104];
  __shared__ bf16 sKV[96][104];
  int t = threadIdx.x;
  float sc = scq[b * 12 + h];
  const float* qsrc = Cq + (size_t)(b * 1024 + n0) * 1920 + h * 96;
  for (int i = t; i < 64 * 24; i += 256) {
    int row = i / 24, seg = (i - row * 24) * 4;
    float4 q4 = *(const float4*)(qsrc + (size_t)row * 1920 + seg);
    bf16x4 o;
    float tv;
    tv = fmaxf(q4.x, 0.f); o[0] = (bf16)(sc * tv * tv * tv);
    tv = fmaxf(q4.y, 0.f); o[1] = (bf16)(sc * tv * tv * tv);
    tv = fmaxf(q4.z, 0.f); o[2] = (bf16)(sc * tv * tv * tv);
    tv = fmaxf(q4.w, 0.f); o[3] = (bf16)(sc * tv * tv * tv);
    *(bf16x4*)&sQ[row][seg] = o;
  }
  const bf16* kvsrc = KVT + (size_t)(b * 4 + kvh) * 9216;
  for (int i = t; i < 96 * 12; i += 256) {
    int row = i / 12, seg = (i - row * 12) * 8;
    *(bf16x8*)&sKV[row][seg] = *(const bf16x8*)(kvsrc + row * 96 + seg);
  }
  __syncthreads();
  int wave = t >> 6, lane = t & 63, quad = lane >> 4, l16 = lane & 15;
  f32x4 acc[6];
  f32x4 zero = {0.f, 0.f, 0.f, 0.f};
#pragma unroll
  for (int j = 0; j < 6; j++) acc[j] = zero;
#pragma unroll
  for (int k0 = 0; k0 < 96; k0 += 32) {
    bf16x8 a = *(const bf16x8*)&sQ[wave * 16 + l16][k0 + quad * 8];
#pragma unroll
    for (int j = 0; j < 6; j++) {
      bf16x8 bb = *(const bf16x8*)&sKV[j * 16 + l16][k0 + quad * 8];
      acc[j] = __builtin_amdgcn_mfma_f32_16x16x32_bf16(a, bb, acc[j], 0, 0, 0);
    }
  }
  const bf16* vd = VD + ((size_t)(b * 4 + kvh) * 1024 + n0) * 96;
  bf16* oc = OC + (size_t)(b * 1024 + n0) * 1152 + h * 96;
#pragma unroll
  for (int j = 0; j < 6; j++) {
    int col = j * 16 + l16;
#pragma unroll
    for (int r = 0; r < 4; r++) {
      int row = wave * 16 + quad * 4 + r;
      float v = acc[j][r] + (float)vd[(size_t)row * 96 + col];
      oc[(size_t)row * 1152 + col] = (bf16)v;
    }
  }
}

// ---------------- launch ----------------
extern "C" void kernel_launch(void* const* d_in, const int* in_sizes, int n_in,
                              void* d_out, int out_size, void* d_ws, size_t ws_size,
                              hipStream_t stream) {
  (void)in_sizes; (void)n_in; (void)out_size; (void)ws_size;
  const void* x      = d_in[0];
  const void* wq_w   = d_in[1];
  const void* wq_b   = d_in[2];
  const void* wkv_w  = d_in[3];
  const void* wkv_b  = d_in[4];
  const void* dwc_w  = d_in[5];
  const void* dwc_b  = d_in[6];
  const void* proj_w = d_in[7];
  const void* proj_b = d_in[8];

  char* ws = (char*)d_ws;
  size_t off = 0;
  auto alloc = [&](size_t bytes) -> void* {
    void* p = ws + off;
    off = (off + bytes + 255) & ~(size_t)255;
    return p;
  };
  int*   flag   = (int*)  alloc(256);
  float* pbuf   = (float*)alloc((size_t)10368 * 4);
  float* facc   = (float*)alloc(1024 * 4);               // 512 groups x (s2,s6)
  float* scale  = (float*)alloc(512 * 4);                // [0,384) q | [384,512) k
  bf16*  wcat_t = (bf16*) alloc((size_t)1920 * 1152 * 2);// [wq_t; wkv_t] rows 0..1919
  bf16*  proj_t = (bf16*) alloc((size_t)1152 * 1152 * 2);
  bf16*  xb     = (bf16*) alloc((size_t)37748736 * 2);   // x bf16 (fp32 mode); reused as out_comb
  float* cq     = (float*)alloc((size_t)32768 * 1920 * 4); // fused q|k|v fp32
  float* part   = (float*)alloc((size_t)1024 * 9216 * 4);  // kv einsum partials
  bf16*  kvt    = (bf16*) alloc((size_t)128 * 9216 * 2);
  bf16*  vdwc   = (bf16*) alloc((size_t)32 * 4 * 1024 * 96 * 2);

  k_detect<<<1, 256, 0, stream>>>((const unsigned int*)x, flag);
  k_prep<<<41, 256, 0, stream>>>(wq_b, wkv_b, dwc_w, dwc_b, proj_b, pbuf, facc, flag);
  k_transpose<<<dim3(36, 36), 256, 0, stream>>>(wq_w, wcat_t, 1152, 1152, flag);
  k_transpose<<<dim3(24, 36), 256, 0, stream>>>(wkv_w, wcat_t + (size_t)1152 * 1152, 1152, 768, flag);
  k_transpose<<<dim3(36, 36), 256, 0, stream>>>(proj_w, proj_t, 1152, 1152, flag);
  k_ingest<<<18432, 256, 0, stream>>>(x, xb, flag);

  const bf16* xbf = (const bf16*)x;

  // fused [q | kv] = x @ [wq | wkv] + b, fp32 out, focus sums fused into epilogue
  k_gemm<<<3840, 256, 0, stream>>>(xb, xbf, 1, wcat_t, pbuf + 0, (void*)cq,
                                   32768, 1920, 1152, 1920, 0, 1, facc, flag);
  k_scales<<<2, 256, 0, stream>>>(facc, scale);

  k_kvein_part<<<1024, 256, 0, stream>>>(cq, part);
  k_kvred<<<4608, 256, 0, stream>>>(part, scale + 384, kvt);

  k_dwc<<<12288, 256, 0, stream>>>(cq, pbuf + 6912, pbuf + 5376, vdwc);
  k_attn<<<dim3(384, 16), 256, 0, stream>>>(cq, scale, kvt, vdwc, xb /* out_comb */);

  // final: out = out_comb @ proj + b  -> d_out (dtype per detected flag)
  k_gemm<<<2304, 256, 0, stream>>>(xb, nullptr, 0, proj_t, pbuf + 5760, d_out,
                                   32768, 1152, 1152, 1152, 1, 0, facc, flag);
}